// Round 1
// baseline (55.752 us; speedup 1.0000x reference)
//
#include <hip/hip_runtime.h>

// Problem constants
constexpr int Bc = 4;
constexpr int Nc = 512;
constexpr int Dc = 512;
constexpr int Pc = 128;

// ---------------------------------------------------------------------------
// Kernel 1: four GEMMs [2048,512]@[512,128] sharing the input activation.
//   m=0: left  = input@Wl + bl          -> ws
//   m=1: right = input@Wr               -> ws
//   m=2: start = relu(input@Ws1+bs1)@Ws2 + bs2  (fused GEMV epilogue)
//   m=3: end   = relu(input@We1+be1)@We2 + be2
// grid (64 row-tiles, 4 matrices), block 256.
// Each block: 32 rows x 128 cols, thread computes 4x4, K-tiled by 32.
// ---------------------------------------------------------------------------
__global__ __launch_bounds__(256) void proj_kernel(
    const float* __restrict__ input,
    const float* __restrict__ Wl,  const float* __restrict__ bl,
    const float* __restrict__ Wr,
    const float* __restrict__ Ws1, const float* __restrict__ bs1,
    const float* __restrict__ Ws2, const float* __restrict__ bs2,
    const float* __restrict__ We1, const float* __restrict__ be1,
    const float* __restrict__ We2, const float* __restrict__ be2,
    float* __restrict__ left, float* __restrict__ right,
    float* __restrict__ start_out, float* __restrict__ end_out)
{
    const int m    = blockIdx.y;
    const int row0 = blockIdx.x * 32;
    const int t    = threadIdx.x;

    const float* W;
    const float* b1;
    switch (m) {
        case 0:  W = Wl;  b1 = bl;      break;
        case 1:  W = Wr;  b1 = nullptr; break;
        case 2:  W = Ws1; b1 = bs1;     break;
        default: W = We1; b1 = be1;     break;
    }

    __shared__ float As[32][32];    // A tile (rows x k)
    __shared__ float Bs[32][128];   // W tile (k x cols)

    float acc[4][4] = {};
    const int r4 = (t >> 5) << 2;   // 0..28 : this thread's 4 rows
    const int c4 = (t & 31) << 2;   // 0..124: this thread's 4 cols

    for (int k0 = 0; k0 < Dc; k0 += 32) {
        // ---- global loads to regs (before the barrier) ----
        const int ar = t >> 3, ak = (t & 7) << 2;
        const float4 av = *(const float4*)&input[(row0 + ar) * Dc + k0 + ak];
        const int wk = t >> 5, wc = (t & 31) << 2;
        float4 wv[4];
        #pragma unroll
        for (int u = 0; u < 4; ++u)
            wv[u] = *(const float4*)&W[(k0 + wk + u * 8) * Pc + wc];

        __syncthreads();            // previous iteration done reading LDS
        *(float4*)&As[ar][ak] = av;
        #pragma unroll
        for (int u = 0; u < 4; ++u)
            *(float4*)&Bs[wk + u * 8][wc] = wv[u];
        __syncthreads();

        // ---- compute ----
        #pragma unroll
        for (int kk = 0; kk < 32; kk += 4) {
            float4 a4[4], w4[4];
            #pragma unroll
            for (int i = 0; i < 4; ++i) a4[i] = *(const float4*)&As[r4 + i][kk];
            #pragma unroll
            for (int q = 0; q < 4; ++q) w4[q] = *(const float4*)&Bs[kk + q][c4];
            #pragma unroll
            for (int i = 0; i < 4; ++i) {
                const float* ap = (const float*)&a4[i];
                #pragma unroll
                for (int q = 0; q < 4; ++q) {
                    const float* wp = (const float*)&w4[q];
                    acc[i][0] = fmaf(ap[q], wp[0], acc[i][0]);
                    acc[i][1] = fmaf(ap[q], wp[1], acc[i][1]);
                    acc[i][2] = fmaf(ap[q], wp[2], acc[i][2]);
                    acc[i][3] = fmaf(ap[q], wp[3], acc[i][3]);
                }
            }
        }
    }

    if (m < 2) {
        // left / right projection: add bias (m==0), store [2048][128]
        float4 bv = make_float4(0.f, 0.f, 0.f, 0.f);
        if (m == 0) bv = *(const float4*)&bl[c4];
        float* outp = (m == 0) ? left : right;
        #pragma unroll
        for (int i = 0; i < 4; ++i) {
            float4 o;
            o.x = acc[i][0] + bv.x; o.y = acc[i][1] + bv.y;
            o.z = acc[i][2] + bv.z; o.w = acc[i][3] + bv.w;
            *(float4*)&outp[(row0 + r4 + i) * Pc + c4] = o;
        }
    } else {
        // start/end: relu(h)@W2 + b2, reduced across the 32 threads of a row
        const float4 bv = *(const float4*)&b1[c4];
        const float* W2 = (m == 2) ? Ws2 : We2;
        const float  b2 = (m == 2) ? bs2[0] : be2[0];
        float* outp     = (m == 2) ? start_out : end_out;
        const float4 w2 = *(const float4*)&W2[c4];
        #pragma unroll
        for (int i = 0; i < 4; ++i) {
            float h0 = fmaxf(acc[i][0] + bv.x, 0.f);
            float h1 = fmaxf(acc[i][1] + bv.y, 0.f);
            float h2 = fmaxf(acc[i][2] + bv.z, 0.f);
            float h3 = fmaxf(acc[i][3] + bv.w, 0.f);
            float p  = h0 * w2.x + h1 * w2.y + h2 * w2.z + h3 * w2.w;
            #pragma unroll
            for (int off = 16; off >= 1; off >>= 1)
                p += __shfl_xor(p, off);
            if ((t & 31) == 0)
                outp[row0 + r4 + i] = p + b2;
        }
    }
}

// ---------------------------------------------------------------------------
// Kernel 2: bigram[b,i,j] = sum_p relu(left[b,j,p] + right[b,i,p]) * Wo[p] + bo
// Tile 64(i) x 32(j) per block, grid (16 jt, 8 it, 4 b) = 512 blocks.
// Thread owns 4(i) x 2(j) outputs; rows map to lanes with stride 1 so padded
// (P+4) LDS stride gives 2-way (free) bank aliasing on ds_read_b128.
// ---------------------------------------------------------------------------
__global__ __launch_bounds__(256) void bigram_kernel(
    const float* __restrict__ left, const float* __restrict__ right,
    const float* __restrict__ Wo,   const float* __restrict__ bo,
    float* __restrict__ out)
{
    const int jt = blockIdx.x, it = blockIdx.y, b = blockIdx.z;
    const int t  = threadIdx.x;

    __shared__ float Ls[32][Pc + 4];
    __shared__ float Rs[64][Pc + 4];
    __shared__ float wos[Pc];

    const float* lb = left  + ((size_t)b * Nc + jt * 32) * Pc;
    const float* rb = right + ((size_t)b * Nc + it * 64) * Pc;

    // stage L tile: 32*128 floats = 1024 float4
    #pragma unroll
    for (int u = 0; u < 4; ++u) {
        int f = t + u * 256;
        int r = f >> 5, p4 = (f & 31) << 2;
        *(float4*)&Ls[r][p4] = *(const float4*)&lb[r * Pc + p4];
    }
    // stage R tile: 64*128 floats = 2048 float4
    #pragma unroll
    for (int u = 0; u < 8; ++u) {
        int f = t + u * 256;
        int r = f >> 5, p4 = (f & 31) << 2;
        *(float4*)&Rs[r][p4] = *(const float4*)&rb[r * Pc + p4];
    }
    if (t < 32) *(float4*)&wos[t << 2] = *(const float4*)&Wo[t << 2];
    __syncthreads();

    const int jl = t & 15;   // j = jl + 16*jj, jj in 0..1
    const int il = t >> 4;   // i = il + 16*ii, ii in 0..3

    float acc[4][2] = {};

    for (int p = 0; p < Pc; p += 4) {
        const float4 wo4 = *(const float4*)&wos[p];
        float4 l4[2], r4[4];
        #pragma unroll
        for (int jj = 0; jj < 2; ++jj) l4[jj] = *(const float4*)&Ls[jl + 16 * jj][p];
        #pragma unroll
        for (int ii = 0; ii < 4; ++ii) r4[ii] = *(const float4*)&Rs[il + 16 * ii][p];
        #pragma unroll
        for (int ii = 0; ii < 4; ++ii) {
            #pragma unroll
            for (int jj = 0; jj < 2; ++jj) {
                acc[ii][jj] = fmaf(fmaxf(l4[jj].x + r4[ii].x, 0.f), wo4.x, acc[ii][jj]);
                acc[ii][jj] = fmaf(fmaxf(l4[jj].y + r4[ii].y, 0.f), wo4.y, acc[ii][jj]);
                acc[ii][jj] = fmaf(fmaxf(l4[jj].z + r4[ii].z, 0.f), wo4.z, acc[ii][jj]);
                acc[ii][jj] = fmaf(fmaxf(l4[jj].w + r4[ii].w, 0.f), wo4.w, acc[ii][jj]);
            }
        }
    }

    const float bias = bo[0];
    #pragma unroll
    for (int ii = 0; ii < 4; ++ii) {
        #pragma unroll
        for (int jj = 0; jj < 2; ++jj) {
            const int gi = it * 64 + il + 16 * ii;
            const int gj = jt * 32 + jl + 16 * jj;
            out[((size_t)b * Nc + gi) * Nc + gj] = acc[ii][jj] + bias;
        }
    }
}

extern "C" void kernel_launch(void* const* d_in, const int* in_sizes, int n_in,
                              void* d_out, int out_size, void* d_ws, size_t ws_size,
                              hipStream_t stream) {
    const float* input = (const float*)d_in[0];
    const float* Wl  = (const float*)d_in[1];
    const float* bl  = (const float*)d_in[2];
    const float* Wr  = (const float*)d_in[3];
    const float* Wo  = (const float*)d_in[4];
    const float* bo  = (const float*)d_in[5];
    const float* Ws1 = (const float*)d_in[6];
    const float* bs1 = (const float*)d_in[7];
    const float* Ws2 = (const float*)d_in[8];
    const float* bs2 = (const float*)d_in[9];
    const float* We1 = (const float*)d_in[10];
    const float* be1 = (const float*)d_in[11];
    const float* We2 = (const float*)d_in[12];
    const float* be2 = (const float*)d_in[13];

    float* out    = (float*)d_out;
    float* bigram = out;                                  // [4*512*512]
    float* start  = out + (size_t)Bc * Nc * Nc;           // [2048]
    float* end    = start + (size_t)Bc * Nc;              // [2048]

    float* left  = (float*)d_ws;                          // [2048*128]
    float* right = left + (size_t)Bc * Nc * Pc;           // [2048*128]

    proj_kernel<<<dim3(64, 4), 256, 0, stream>>>(
        input, Wl, bl, Wr, Ws1, bs1, Ws2, bs2, We1, be1, We2, be2,
        left, right, start, end);

    bigram_kernel<<<dim3(16, 8, 4), 256, 0, stream>>>(
        left, right, Wo, bo, bigram);
}

// Round 2
// 46.889 us; speedup vs baseline: 1.1890x; 1.1890x over previous
//
#include <hip/hip_runtime.h>

constexpr int Bc = 4;
constexpr int Nc = 512;
constexpr int Dc = 512;
constexpr int Pc = 128;
constexpr int ROWS = Bc * Nc;   // 2048

// ---------------------------------------------------------------------------
// proj: 4 GEMMs [2048,512]@[512,128] sharing input.
// grid (64 rowtiles, 2 coltiles, 4 mats) = 512 blocks, 256 threads.
// Tile 32 rows x 64 cols, thread = 2r x 4c. BK=32, K pipelined via registers.
//   m=0: left  = input@Wl + bl
//   m=1: right = input@Wr
//   m=2/3: per-row partial of relu(input@W1+b1)@W2 over this block's 64 cols
//          -> parts[pi*2048 + row]  (pi = (m-2)*2 + coltile)
// ---------------------------------------------------------------------------
__global__ __launch_bounds__(256) void proj_kernel(
    const float* __restrict__ input,
    const float* __restrict__ Wl,  const float* __restrict__ bl,
    const float* __restrict__ Wr,
    const float* __restrict__ Ws1, const float* __restrict__ bs1,
    const float* __restrict__ Ws2,
    const float* __restrict__ We1, const float* __restrict__ be1,
    const float* __restrict__ We2,
    float* __restrict__ left, float* __restrict__ right,
    float* __restrict__ parts)
{
    const int m    = blockIdx.z;
    const int c0   = blockIdx.y * 64;
    const int row0 = blockIdx.x * 32;
    const int t    = threadIdx.x;

    const float* W = (m == 0) ? Wl : (m == 1) ? Wr : (m == 2) ? Ws1 : We1;

    __shared__ float As[32][36];   // stride 36: bank offset 4/row
    __shared__ float Bs[32][68];   // stride 68: bank offset 4/row

    const int cg = t & 15, rg = t >> 4;
    const int c4 = cg << 2;        // local col 0..60
    const int r2 = rg << 1;        // local row 0..30

    // staging indices
    const int ar = t >> 3, ak = (t & 7) << 2;          // A: 32 rows x 8 f4
    const int wr = t >> 4, wc = (t & 15) << 2;         // W: 16 k-rows x 16 f4 (x2)

    const float* Ap = input + (size_t)(row0 + ar) * Dc + ak;
    const float* Wp = W + (size_t)wr * Pc + c0 + wc;

    float4 aReg  = *(const float4*)Ap;
    float4 wReg0 = *(const float4*)Wp;
    float4 wReg1 = *(const float4*)(Wp + 16 * Pc);

    float acc[2][4] = {};

    for (int k0 = 0; k0 < Dc; k0 += 32) {
        __syncthreads();                       // prev iter done reading LDS
        *(float4*)&As[ar][ak]      = aReg;
        *(float4*)&Bs[wr][wc]      = wReg0;
        *(float4*)&Bs[wr + 16][wc] = wReg1;
        __syncthreads();

        if (k0 + 32 < Dc) {                    // prefetch next K-tile
            aReg  = *(const float4*)(Ap + k0 + 32);
            wReg0 = *(const float4*)(Wp + (size_t)(k0 + 32) * Pc);
            wReg1 = *(const float4*)(Wp + (size_t)(k0 + 48) * Pc);
        }

        #pragma unroll 4
        for (int kk = 0; kk < 32; kk += 4) {
            float4 a0 = *(const float4*)&As[r2][kk];
            float4 a1 = *(const float4*)&As[r2 + 1][kk];
            float4 w0 = *(const float4*)&Bs[kk + 0][c4];
            float4 w1 = *(const float4*)&Bs[kk + 1][c4];
            float4 w2 = *(const float4*)&Bs[kk + 2][c4];
            float4 w3 = *(const float4*)&Bs[kk + 3][c4];
            const float* a0p = (const float*)&a0;
            const float* a1p = (const float*)&a1;
            const float4 wv[4] = {w0, w1, w2, w3};
            #pragma unroll
            for (int s = 0; s < 4; ++s) {
                acc[0][0] = fmaf(a0p[s], wv[s].x, acc[0][0]);
                acc[0][1] = fmaf(a0p[s], wv[s].y, acc[0][1]);
                acc[0][2] = fmaf(a0p[s], wv[s].z, acc[0][2]);
                acc[0][3] = fmaf(a0p[s], wv[s].w, acc[0][3]);
                acc[1][0] = fmaf(a1p[s], wv[s].x, acc[1][0]);
                acc[1][1] = fmaf(a1p[s], wv[s].y, acc[1][1]);
                acc[1][2] = fmaf(a1p[s], wv[s].z, acc[1][2]);
                acc[1][3] = fmaf(a1p[s], wv[s].w, acc[1][3]);
            }
        }
    }

    if (m < 2) {
        float4 bv = make_float4(0.f, 0.f, 0.f, 0.f);
        if (m == 0) bv = *(const float4*)&bl[c0 + c4];
        float* outp = (m == 0) ? left : right;
        #pragma unroll
        for (int i = 0; i < 2; ++i) {
            float4 o;
            o.x = acc[i][0] + bv.x; o.y = acc[i][1] + bv.y;
            o.z = acc[i][2] + bv.z; o.w = acc[i][3] + bv.w;
            *(float4*)&outp[(size_t)(row0 + r2 + i) * Pc + c0 + c4] = o;
        }
    } else {
        const float* b1 = (m == 2) ? bs1 : be1;
        const float* W2 = (m == 2) ? Ws2 : We2;
        const float4 bv  = *(const float4*)&b1[c0 + c4];
        const float4 w2v = *(const float4*)&W2[c0 + c4];
        const int pi = (m - 2) * 2 + blockIdx.y;
        #pragma unroll
        for (int i = 0; i < 2; ++i) {
            float p = fmaxf(acc[i][0] + bv.x, 0.f) * w2v.x
                    + fmaxf(acc[i][1] + bv.y, 0.f) * w2v.y
                    + fmaxf(acc[i][2] + bv.z, 0.f) * w2v.z
                    + fmaxf(acc[i][3] + bv.w, 0.f) * w2v.w;
            p += __shfl_xor(p, 1);
            p += __shfl_xor(p, 2);
            p += __shfl_xor(p, 4);
            p += __shfl_xor(p, 8);
            if (cg == 0) parts[pi * ROWS + row0 + r2 + i] = p;
        }
    }
}

// ---------------------------------------------------------------------------
// bigram[b,i,j] = sum_p relu(left[b,j,p] + right[b,i,p]) * Wo[p] + bo
// grid (9, 16, 4): jt<8 -> 32i x 64j tiles, thread = 2i x 4j, ping-pong p-loop.
// jt==8 (it<8): combine start/end partials.
// ---------------------------------------------------------------------------
__global__ __launch_bounds__(256) void bigram_kernel(
    const float* __restrict__ left, const float* __restrict__ right,
    const float* __restrict__ Wo,   const float* __restrict__ bo,
    const float* __restrict__ parts,
    const float* __restrict__ bs2,  const float* __restrict__ be2,
    float* __restrict__ out, float* __restrict__ start_out,
    float* __restrict__ end_out)
{
    const int jt = blockIdx.x, it = blockIdx.y, b = blockIdx.z;
    const int t  = threadIdx.x;

    if (jt == 8) {
        if (it >= 8) return;
        const int base = (b * 8 + it) * 64;
        if (t < 64) {
            const int r = base + t;
            start_out[r] = parts[r] + parts[ROWS + r] + bs2[0];
        } else if (t < 128) {
            const int r = base + t - 64;
            end_out[r] = parts[2 * ROWS + r] + parts[3 * ROWS + r] + be2[0];
        }
        return;
    }

    __shared__ float Ls[64][132];
    __shared__ float Rs[32][132];
    __shared__ float wos[Pc];

    const float* lp = left  + (size_t)(b * Nc + jt * 64) * Pc;
    const float* rp = right + (size_t)(b * Nc + it * 32) * Pc;

    #pragma unroll
    for (int u = 0; u < 8; ++u) {
        int f = t + u * 256, r = f >> 5, p4 = (f & 31) << 2;
        *(float4*)&Ls[r][p4] = *(const float4*)&lp[r * Pc + p4];
    }
    #pragma unroll
    for (int u = 0; u < 4; ++u) {
        int f = t + u * 256, r = f >> 5, p4 = (f & 31) << 2;
        *(float4*)&Rs[r][p4] = *(const float4*)&rp[r * Pc + p4];
    }
    if (t < 32) *(float4*)&wos[t << 2] = *(const float4*)&Wo[t << 2];
    __syncthreads();

    const int jl = t & 15;   // j = jl + 16*jj
    const int il = t >> 4;   // i = il + 16*ii (il 0..15, ii 0..1)

    float acc[2][4] = {};

#define LOADG(P, W4, L4, R4)                                             \
    {                                                                    \
        W4 = *(const float4*)&wos[(P)];                                  \
        _Pragma("unroll") for (int jj = 0; jj < 4; ++jj)                 \
            L4[jj] = *(const float4*)&Ls[jl + 16 * jj][(P)];             \
        _Pragma("unroll") for (int ii = 0; ii < 2; ++ii)                 \
            R4[ii] = *(const float4*)&Rs[il + 16 * ii][(P)];             \
    }

#define COMPUTE(W4, L4, R4)                                              \
    {                                                                    \
        _Pragma("unroll") for (int ii = 0; ii < 2; ++ii)                 \
        _Pragma("unroll") for (int jj = 0; jj < 4; ++jj) {               \
            acc[ii][jj] = fmaf(fmaxf(L4[jj].x + R4[ii].x, 0.f), W4.x, acc[ii][jj]); \
            acc[ii][jj] = fmaf(fmaxf(L4[jj].y + R4[ii].y, 0.f), W4.y, acc[ii][jj]); \
            acc[ii][jj] = fmaf(fmaxf(L4[jj].z + R4[ii].z, 0.f), W4.z, acc[ii][jj]); \
            acc[ii][jj] = fmaf(fmaxf(L4[jj].w + R4[ii].w, 0.f), W4.w, acc[ii][jj]); \
        }                                                                \
    }

    float4 wa, la[4], ra[2];
    float4 wb, lb4[4], rb4[2];
    LOADG(0, wa, la, ra);

    #pragma unroll 1
    for (int p = 0; p < Pc; p += 8) {
        LOADG(p + 4, wb, lb4, rb4);
        COMPUTE(wa, la, ra);
        if (p + 8 < Pc) LOADG(p + 8, wa, la, ra);
        COMPUTE(wb, lb4, rb4);
    }

    const float bias = bo[0];
    #pragma unroll
    for (int ii = 0; ii < 2; ++ii) {
        #pragma unroll
        for (int jj = 0; jj < 4; ++jj) {
            const int gi = it * 32 + il + 16 * ii;
            const int gj = jt * 64 + jl + 16 * jj;
            out[((size_t)b * Nc + gi) * Nc + gj] = acc[ii][jj] + bias;
        }
    }
#undef LOADG
#undef COMPUTE
}

extern "C" void kernel_launch(void* const* d_in, const int* in_sizes, int n_in,
                              void* d_out, int out_size, void* d_ws, size_t ws_size,
                              hipStream_t stream) {
    const float* input = (const float*)d_in[0];
    const float* Wl  = (const float*)d_in[1];
    const float* bl  = (const float*)d_in[2];
    const float* Wr  = (const float*)d_in[3];
    const float* Wo  = (const float*)d_in[4];
    const float* bo  = (const float*)d_in[5];
    const float* Ws1 = (const float*)d_in[6];
    const float* bs1 = (const float*)d_in[7];
    const float* Ws2 = (const float*)d_in[8];
    const float* bs2 = (const float*)d_in[9];
    const float* We1 = (const float*)d_in[10];
    const float* be1 = (const float*)d_in[11];
    const float* We2 = (const float*)d_in[12];
    const float* be2 = (const float*)d_in[13];

    float* out    = (float*)d_out;
    float* bigram = out;
    float* start  = out + (size_t)Bc * Nc * Nc;
    float* end    = start + (size_t)Bc * Nc;

    float* left  = (float*)d_ws;                      // 2048*128
    float* right = left + (size_t)ROWS * Pc;          // 2048*128
    float* parts = right + (size_t)ROWS * Pc;         // 4*2048

    proj_kernel<<<dim3(64, 2, 4), 256, 0, stream>>>(
        input, Wl, bl, Wr, Ws1, bs1, Ws2, We1, be1, We2,
        left, right, parts);

    bigram_kernel<<<dim3(9, 16, 4), 256, 0, stream>>>(
        left, right, Wo, bo, parts, bs2, be2, bigram, start, end);
}

// Round 3
// 37.658 us; speedup vs baseline: 1.4805x; 1.2451x over previous
//
#include <hip/hip_runtime.h>

typedef unsigned short ushort_t;
using f32x4  = __attribute__((ext_vector_type(4))) float;
using bf16x8 = __attribute__((ext_vector_type(8))) short;
using u16x8  = __attribute__((ext_vector_type(8))) unsigned short;

constexpr int Bc = 4;
constexpr int Nc = 512;
constexpr int Dc = 512;
constexpr int Pc = 128;
constexpr int ROWS = Bc * Nc;   // 2048

__device__ inline unsigned short f2bf(float f) {
    unsigned u = __builtin_bit_cast(unsigned, f);
    unsigned r = u + 0x7fffu + ((u >> 16) & 1u);   // RNE
    return (unsigned short)(r >> 16);
}

// ---------------------------------------------------------------------------
// convert: blocks 0..63 -> WcatT[512 col][512 k] bf16 (LDS-tiled transpose of
// [Wl|Wr|Ws1|We1]); blocks 64..575 -> input fp32 -> bf16 [2048x512].
// ---------------------------------------------------------------------------
__global__ __launch_bounds__(256) void convert_kernel(
    const float* __restrict__ input,
    const float* __restrict__ Wl,  const float* __restrict__ Wr,
    const float* __restrict__ Ws1, const float* __restrict__ We1,
    ushort_t* __restrict__ inBF, ushort_t* __restrict__ WcatT)
{
    const int bx = blockIdx.x, t = threadIdx.x;
    if (bx < 64) {
        const int ct = bx >> 3, kt = bx & 7;       // 8 col-tiles x 8 k-tiles of 64
        const int c0 = ct * 64, k0 = kt * 64;
        const int mi = c0 >> 7;
        const float* Wm = (mi == 0) ? Wl : (mi == 1) ? Wr : (mi == 2) ? Ws1 : We1;
        const int cm0 = c0 & 127;

        __shared__ float T[64][68];
        const int kk = t >> 4, cc = (t & 15) << 2;
        #pragma unroll
        for (int u = 0; u < 4; ++u)
            *(float4*)&T[kk + u * 16][cc] =
                *(const float4*)&Wm[(size_t)(k0 + kk + u * 16) * Pc + cm0 + cc];
        __syncthreads();

        const int c_l = t >> 2, kb = (t & 3) << 4;   // 64 cols x 4 k-chunks of 16
        u16x8 o0, o1;
        #pragma unroll
        for (int u = 0; u < 8; ++u) o0[u] = f2bf(T[kb + u][c_l]);
        #pragma unroll
        for (int u = 0; u < 8; ++u) o1[u] = f2bf(T[kb + 8 + u][c_l]);
        ushort_t* dst = &WcatT[(size_t)(c0 + c_l) * Dc + k0 + kb];
        *(u16x8*)dst = o0;
        *(u16x8*)(dst + 8) = o1;
    } else {
        const size_t idx0 = (size_t)(bx - 64) * 2048 + (size_t)t * 8;
        float4 v0 = *(const float4*)&input[idx0];
        float4 v1 = *(const float4*)&input[idx0 + 4];
        u16x8 o;
        o[0] = f2bf(v0.x); o[1] = f2bf(v0.y); o[2] = f2bf(v0.z); o[3] = f2bf(v0.w);
        o[4] = f2bf(v1.x); o[5] = f2bf(v1.y); o[6] = f2bf(v1.z); o[7] = f2bf(v1.w);
        *(u16x8*)&inBF[idx0] = o;
    }
}

// ---------------------------------------------------------------------------
// mfma_proj: C[2048,512] = inBF @ WcatT^T via mfma_f32_16x16x32_bf16.
// grid (32 mt, 8 ny), 256 thr = 4 waves (2M x 2N quadrants of 32x32).
// Tile 64x64, BK=64, single LDS buffer, prefetch next K-tile in regs.
// LDS layout [x][64k] bf16 with XOR swizzle (kbyte ^= (row&7)<<4) on both
// write and read: breaks the 128B-row-stride 16-way bank conflict.
// ny 0..3 -> left/right to ws; ny 4..7 -> start/end partial dots to parts.
// ---------------------------------------------------------------------------
__device__ inline ushort_t* swz(ushort_t* base, int row, int kbyte) {
    return (ushort_t*)((char*)base + row * 128 + (kbyte ^ ((row & 7) << 4)));
}

__global__ __launch_bounds__(256) void mfma_proj_kernel(
    const ushort_t* __restrict__ inBF, const ushort_t* __restrict__ WcatT,
    const float* __restrict__ bl,
    const float* __restrict__ bs1, const float* __restrict__ Ws2,
    const float* __restrict__ be1, const float* __restrict__ We2,
    float* __restrict__ left, float* __restrict__ right,
    float* __restrict__ parts)
{
    const int mt = blockIdx.x, ny = blockIdx.y;
    const int row0 = mt * 64, col0 = ny * 64;
    const int t = threadIdx.x;
    const int w = t >> 6, l = t & 63;
    const int wm = w >> 1, wn = w & 1;

    __shared__ ushort_t As[64 * 64];
    __shared__ ushort_t Bs[64 * 64];
    __shared__ float red[2][64];

    f32x4 acc[2][2];
    #pragma unroll
    for (int m = 0; m < 2; ++m)
        #pragma unroll
        for (int n = 0; n < 2; ++n)
            acc[m][n] = f32x4{0.f, 0.f, 0.f, 0.f};

    // staging: thread -> row sr (0..63), 32B chunk (t&3)
    const int sr = t >> 2;
    const int kb0 = (t & 3) << 5;                 // byte offset within 128B row
    const ushort_t* Ag = inBF  + (size_t)(row0 + sr) * Dc + (kb0 >> 1);
    const ushort_t* Bg = WcatT + (size_t)(col0 + sr) * Dc + (kb0 >> 1);

    float4 aR0 = *(const float4*)Ag,       aR1 = *(const float4*)(Ag + 8);
    float4 bR0 = *(const float4*)Bg,       bR1 = *(const float4*)(Bg + 8);

    const int fr = l & 15, fg = l >> 4;

    for (int ks = 0; ks < 8; ++ks) {
        *(float4*)swz(As, sr, kb0)      = aR0;
        *(float4*)swz(As, sr, kb0 + 16) = aR1;
        *(float4*)swz(Bs, sr, kb0)      = bR0;
        *(float4*)swz(Bs, sr, kb0 + 16) = bR1;
        __syncthreads();

        if (ks < 7) {
            const ushort_t* Ag2 = Ag + (ks + 1) * 64;
            const ushort_t* Bg2 = Bg + (ks + 1) * 64;
            aR0 = *(const float4*)Ag2; aR1 = *(const float4*)(Ag2 + 8);
            bR0 = *(const float4*)Bg2; bR1 = *(const float4*)(Bg2 + 8);
        }

        #pragma unroll
        for (int kk = 0; kk < 2; ++kk) {
            bf16x8 a0 = *(bf16x8*)swz(As, wm * 32 + fr,      kk * 64 + fg * 16);
            bf16x8 a1 = *(bf16x8*)swz(As, wm * 32 + 16 + fr, kk * 64 + fg * 16);
            bf16x8 b0 = *(bf16x8*)swz(Bs, wn * 32 + fr,      kk * 64 + fg * 16);
            bf16x8 b1 = *(bf16x8*)swz(Bs, wn * 32 + 16 + fr, kk * 64 + fg * 16);
            acc[0][0] = __builtin_amdgcn_mfma_f32_16x16x32_bf16(a0, b0, acc[0][0], 0, 0, 0);
            acc[0][1] = __builtin_amdgcn_mfma_f32_16x16x32_bf16(a0, b1, acc[0][1], 0, 0, 0);
            acc[1][0] = __builtin_amdgcn_mfma_f32_16x16x32_bf16(a1, b0, acc[1][0], 0, 0, 0);
            acc[1][1] = __builtin_amdgcn_mfma_f32_16x16x32_bf16(a1, b1, acc[1][1], 0, 0, 0);
        }
        __syncthreads();
    }

    const int fq4 = fg << 2;    // D row base = (lane>>4)*4
    if (ny < 4) {
        float* outp = (ny < 2) ? left : right;
        const int cbase = (ny & 1) * 64 + wn * 32;
        #pragma unroll
        for (int m = 0; m < 2; ++m) {
            const int row = row0 + wm * 32 + m * 16 + fq4;
            #pragma unroll
            for (int n = 0; n < 2; ++n) {
                const int col = cbase + n * 16 + fr;
                const float bv = (ny < 2) ? bl[col] : 0.f;
                #pragma unroll
                for (int q = 0; q < 4; ++q)
                    outp[(size_t)(row + q) * Pc + col] = acc[m][n][q] + bv;
            }
        }
    } else {
        const float* b1 = (ny < 6) ? bs1 : be1;
        const float* W2 = (ny < 6) ? Ws2 : We2;
        const int pbase = (ny < 6) ? (ny - 4) * 64 : (ny - 6) * 64;
        float vs[2][4];
        #pragma unroll
        for (int m = 0; m < 2; ++m)
            #pragma unroll
            for (int q = 0; q < 4; ++q) {
                float v = 0.f;
                #pragma unroll
                for (int n = 0; n < 2; ++n) {
                    const int cp = pbase + wn * 32 + n * 16 + fr;
                    v += fmaxf(acc[m][n][q] + b1[cp], 0.f) * W2[cp];
                }
                v += __shfl_xor(v, 1);
                v += __shfl_xor(v, 2);
                v += __shfl_xor(v, 4);
                v += __shfl_xor(v, 8);
                vs[m][q] = v;
            }
        if (fr == 0) {
            #pragma unroll
            for (int m = 0; m < 2; ++m)
                #pragma unroll
                for (int q = 0; q < 4; ++q)
                    red[wn][wm * 32 + m * 16 + fq4 + q] = vs[m][q];
        }
        __syncthreads();
        if (t < 64) {
            const int pi = ny - 4;
            parts[pi * ROWS + row0 + t] = red[0][t] + red[1][t];
        }
    }
}

// ---------------------------------------------------------------------------
// bigram (unchanged control): 32i x 64j tiles, thread = 2i x 4j, ping-pong.
// jt==8 blocks combine start/end partials.
// ---------------------------------------------------------------------------
__global__ __launch_bounds__(256) void bigram_kernel(
    const float* __restrict__ left, const float* __restrict__ right,
    const float* __restrict__ Wo,   const float* __restrict__ bo,
    const float* __restrict__ parts,
    const float* __restrict__ bs2,  const float* __restrict__ be2,
    float* __restrict__ out, float* __restrict__ start_out,
    float* __restrict__ end_out)
{
    const int jt = blockIdx.x, it = blockIdx.y, b = blockIdx.z;
    const int t  = threadIdx.x;

    if (jt == 8) {
        if (it >= 8) return;
        const int base = (b * 8 + it) * 64;
        if (t < 64) {
            const int r = base + t;
            start_out[r] = parts[r] + parts[ROWS + r] + bs2[0];
        } else if (t < 128) {
            const int r = base + t - 64;
            end_out[r] = parts[2 * ROWS + r] + parts[3 * ROWS + r] + be2[0];
        }
        return;
    }

    __shared__ float Ls[64][132];
    __shared__ float Rs[32][132];
    __shared__ float wos[Pc];

    const float* lp = left  + (size_t)(b * Nc + jt * 64) * Pc;
    const float* rp = right + (size_t)(b * Nc + it * 32) * Pc;

    #pragma unroll
    for (int u = 0; u < 8; ++u) {
        int f = t + u * 256, r = f >> 5, p4 = (f & 31) << 2;
        *(float4*)&Ls[r][p4] = *(const float4*)&lp[r * Pc + p4];
    }
    #pragma unroll
    for (int u = 0; u < 4; ++u) {
        int f = t + u * 256, r = f >> 5, p4 = (f & 31) << 2;
        *(float4*)&Rs[r][p4] = *(const float4*)&rp[r * Pc + p4];
    }
    if (t < 32) *(float4*)&wos[t << 2] = *(const float4*)&Wo[t << 2];
    __syncthreads();

    const int jl = t & 15;
    const int il = t >> 4;

    float acc[2][4] = {};

#define LOADG(P, W4, L4, R4)                                             \
    {                                                                    \
        W4 = *(const float4*)&wos[(P)];                                  \
        _Pragma("unroll") for (int jj = 0; jj < 4; ++jj)                 \
            L4[jj] = *(const float4*)&Ls[jl + 16 * jj][(P)];             \
        _Pragma("unroll") for (int ii = 0; ii < 2; ++ii)                 \
            R4[ii] = *(const float4*)&Rs[il + 16 * ii][(P)];             \
    }

#define COMPUTE(W4, L4, R4)                                              \
    {                                                                    \
        _Pragma("unroll") for (int ii = 0; ii < 2; ++ii)                 \
        _Pragma("unroll") for (int jj = 0; jj < 4; ++jj) {               \
            acc[ii][jj] = fmaf(fmaxf(L4[jj].x + R4[ii].x, 0.f), W4.x, acc[ii][jj]); \
            acc[ii][jj] = fmaf(fmaxf(L4[jj].y + R4[ii].y, 0.f), W4.y, acc[ii][jj]); \
            acc[ii][jj] = fmaf(fmaxf(L4[jj].z + R4[ii].z, 0.f), W4.z, acc[ii][jj]); \
            acc[ii][jj] = fmaf(fmaxf(L4[jj].w + R4[ii].w, 0.f), W4.w, acc[ii][jj]); \
        }                                                                \
    }

    float4 wa, la[4], ra[2];
    float4 wb, lb4[4], rb4[2];
    LOADG(0, wa, la, ra);

    #pragma unroll 1
    for (int p = 0; p < Pc; p += 8) {
        LOADG(p + 4, wb, lb4, rb4);
        COMPUTE(wa, la, ra);
        if (p + 8 < Pc) LOADG(p + 8, wa, la, ra);
        COMPUTE(wb, lb4, rb4);
    }

    const float bias = bo[0];
    #pragma unroll
    for (int ii = 0; ii < 2; ++ii) {
        #pragma unroll
        for (int jj = 0; jj < 4; ++jj) {
            const int gi = it * 32 + il + 16 * ii;
            const int gj = jt * 64 + jl + 16 * jj;
            out[((size_t)b * Nc + gi) * Nc + gj] = acc[ii][jj] + bias;
        }
    }
#undef LOADG
#undef COMPUTE
}

extern "C" void kernel_launch(void* const* d_in, const int* in_sizes, int n_in,
                              void* d_out, int out_size, void* d_ws, size_t ws_size,
                              hipStream_t stream) {
    const float* input = (const float*)d_in[0];
    const float* Wl  = (const float*)d_in[1];
    const float* bl  = (const float*)d_in[2];
    const float* Wr  = (const float*)d_in[3];
    const float* Wo  = (const float*)d_in[4];
    const float* bo  = (const float*)d_in[5];
    const float* Ws1 = (const float*)d_in[6];
    const float* bs1 = (const float*)d_in[7];
    const float* Ws2 = (const float*)d_in[8];
    const float* bs2 = (const float*)d_in[9];
    const float* We1 = (const float*)d_in[10];
    const float* be1 = (const float*)d_in[11];
    const float* We2 = (const float*)d_in[12];
    const float* be2 = (const float*)d_in[13];

    float* out    = (float*)d_out;
    float* bigram = out;
    float* start  = out + (size_t)Bc * Nc * Nc;
    float* end    = start + (size_t)Bc * Nc;

    float* left   = (float*)d_ws;                       // 2048*128 f
    float* right  = left + (size_t)ROWS * Pc;           // 2048*128 f
    float* parts  = right + (size_t)ROWS * Pc;          // 4*2048 f
    ushort_t* inBF  = (ushort_t*)(parts + 4 * ROWS);    // 2048*512 bf16
    ushort_t* WcatT = inBF + (size_t)ROWS * Dc;         // 512*512 bf16

    convert_kernel<<<576, 256, 0, stream>>>(input, Wl, Wr, Ws1, We1, inBF, WcatT);

    mfma_proj_kernel<<<dim3(32, 8), 256, 0, stream>>>(
        inBF, WcatT, bl, bs1, Ws2, be1, We2, left, right, parts);

    bigram_kernel<<<dim3(9, 16, 4), 256, 0, stream>>>(
        left, right, Wo, bo, parts, bs2, be2, bigram, start, end);
}